// Round 1
// baseline (3563.877 us; speedup 1.0000x reference)
//
#include <hip/hip_runtime.h>
#include <hip/hip_bf16.h>

#define NN 1024

// ---------------------------------------------------------------------------
// Kernel 1: primes[i] = BASE_PRIMES[argmax_ch feat[0, ch, i, 0]]  (first-max)
// ---------------------------------------------------------------------------
__global__ void primes_kernel(const float* __restrict__ feat, int* __restrict__ primes) {
    int i = blockIdx.x * blockDim.x + threadIdx.x;
    if (i < NN) {
        float best = feat[i * NN];   // ch=0, col=0
        int arg = 0;
        for (int ch = 1; ch < 4; ++ch) {
            float v = feat[ch * NN * NN + i * NN];
            if (v > best) { best = v; arg = ch; }   // strict > keeps first max
        }
        const int P[4] = {2, 3, 5, 7};
        primes[i] = P[arg];
    }
}

// ---------------------------------------------------------------------------
// Kernel 2: S = premask(con); zero R, C, out
// ---------------------------------------------------------------------------
__global__ void prep_kernel(const float* __restrict__ con, const int* __restrict__ primes,
                            float* __restrict__ S, double* __restrict__ R,
                            double* __restrict__ C, float* __restrict__ out) {
    int idx = blockIdx.x * blockDim.x + threadIdx.x;
    int i = idx >> 10;
    int j = idx & (NN - 1);
    float c = (con[idx] + con[j * NN + i]) * 0.5f;   // bitwise same as jnp fp32
    int prod = primes[i] * primes[j];
    bool canon = (prod == 14) | (prod == 15) | (prod == 35);
    int d = i - j; if (d < 0) d = -d;
    bool dist_ok = d >= 4;
    S[idx] = (canon && dist_ok) ? c : 0.0f;
    R[idx] = 0.0;
    C[idx] = 0.0;
    out[idx] = 0.0f;
}

// ---------------------------------------------------------------------------
// Kernel 3: one anti-diagonal of the Nussinov DP.
//   cell i (block) computes V(i, i+d) = max(pair, max_k V(i,k)+V(k+1,j))
//   R[i*N+j] = V(i,j) row-major; C[j*N+i] = V(i,j) transposed (coalesced col).
// All candidate values are single two-operand fp64 adds -> bitwise == numpy.
// ---------------------------------------------------------------------------
__global__ __launch_bounds__(256) void diag_kernel(double* __restrict__ R,
                                                   double* __restrict__ C,
                                                   const float* __restrict__ S, int d) {
    int i = blockIdx.x;
    int j = i + d;
    double best = -1.0;   // all candidates >= 0
    for (int k = i + threadIdx.x; k < j; k += 256)
        best = fmax(best, R[i * NN + k] + C[j * NN + k + 1]);
    // wave reduce (64 lanes)
    for (int off = 32; off; off >>= 1)
        best = fmax(best, __shfl_down(best, off));
    __shared__ double sred[4];
    if ((threadIdx.x & 63) == 0) sred[threadIdx.x >> 6] = best;
    __syncthreads();
    if (threadIdx.x == 0) {
        best = fmax(fmax(sred[0], sred[1]), fmax(sred[2], sred[3]));
        double pair = (d >= 2 ? R[(i + 1) * NN + (j - 1)] : 0.0) + (double)S[i * NN + j];
        double val = fmax(best, pair);
        R[i * NN + j] = val;
        C[j * NN + i] = val;
    }
}

// ---------------------------------------------------------------------------
// Kernel 4: stack traceback (single block). Thread 0 drives the O(1) cases;
// the whole block does the parallel first-max argmax for split events.
// Writes out[i*N+j] = out[j*N+i] = S[i*N+j] at chosen pairs.
// ---------------------------------------------------------------------------
__global__ __launch_bounds__(256) void traceback_kernel(const double* __restrict__ R,
                                                        const double* __restrict__ C,
                                                        const float* __restrict__ S,
                                                        float* __restrict__ out) {
    __shared__ int stk_i[2048];
    __shared__ int stk_j[2048];
    __shared__ int sh_top, sh_ii, sh_jj, sh_cmd;
    __shared__ double sred_v[4];
    __shared__ int sred_k[4];
    const double eps = 1e-9;

    if (threadIdx.x == 0) {
        sh_top = 1; stk_i[0] = 0; stk_j[0] = NN - 1;
    }
    __syncthreads();

    while (true) {
        if (threadIdx.x == 0) {
            int cmd = -1;
            int top = sh_top;
            while (top > 0) {
                int i = stk_i[--top];
                int j = stk_j[top];
                if (j <= i) continue;
                double v = R[i * NN + j];
                if (v <= eps) continue;
                if (R[(i + 1) * NN + j] >= v - eps) {      // i unpaired
                    stk_i[top] = i + 1; stk_j[top] = j; ++top;
                    continue;
                }
                float sv = S[i * NN + j];
                if (sv > 0.0f && R[(i + 1) * NN + (j - 1)] + (double)sv >= v - eps) {
                    out[i * NN + j] = sv;                  // pair (i,j)
                    out[j * NN + i] = sv;
                    stk_i[top] = i + 1; stk_j[top] = j - 1; ++top;
                    continue;
                }
                sh_ii = i; sh_jj = j; cmd = 0;             // need split argmax
                break;
            }
            sh_top = top;
            sh_cmd = cmd;
        }
        __syncthreads();
        if (sh_cmd < 0) break;
        int i = sh_ii, j = sh_jj;

        // parallel argmax over k in [i, j-1]; tie -> smallest k (np.argmax)
        double bv = -1.0;
        int bk = 0x7fffffff;
        for (int k = i + threadIdx.x; k < j; k += 256) {
            double t = R[i * NN + k] + C[j * NN + k + 1];
            if (t > bv) { bv = t; bk = k; }   // strided: each thread's ties keep lowest k
        }
        for (int off = 32; off; off >>= 1) {
            double ov = __shfl_down(bv, off);
            int   ok = __shfl_down(bk, off);
            if (ov > bv || (ov == bv && ok < bk)) { bv = ov; bk = ok; }
        }
        if ((threadIdx.x & 63) == 0) { sred_v[threadIdx.x >> 6] = bv; sred_k[threadIdx.x >> 6] = bk; }
        __syncthreads();
        if (threadIdx.x == 0) {
            double fv = sred_v[0]; int fk = sred_k[0];
            for (int w = 1; w < 4; ++w)
                if (sred_v[w] > fv || (sred_v[w] == fv && sred_k[w] < fk)) { fv = sred_v[w]; fk = sred_k[w]; }
            int top = sh_top;
            stk_i[top] = i;      stk_j[top] = fk; ++top;   // pushed first
            stk_i[top] = fk + 1; stk_j[top] = j;  ++top;   // popped first
            sh_top = top;
        }
        __syncthreads();
    }
}

// ---------------------------------------------------------------------------
extern "C" void kernel_launch(void* const* d_in, const int* in_sizes, int n_in,
                              void* d_out, int out_size, void* d_ws, size_t ws_size,
                              hipStream_t stream) {
    const float* con  = (const float*)d_in[0];   // (1,1,1024,1024) fp32
    const float* feat = (const float*)d_in[1];   // (1,16,1024,1024) fp32
    float* out = (float*)d_out;                  // (1,1,1024,1024) fp32

    char* ws = (char*)d_ws;
    double* R      = (double*)(ws);                          // 8 MB
    double* C      = (double*)(ws + (size_t)8  * 1024 * 1024); // 8 MB
    float*  S      = (float*) (ws + (size_t)16 * 1024 * 1024); // 4 MB
    int*    primes = (int*)   (ws + (size_t)20 * 1024 * 1024); // 4 KB

    primes_kernel<<<(NN + 255) / 256, 256, 0, stream>>>(feat, primes);
    prep_kernel<<<(NN * NN) / 256, 256, 0, stream>>>(con, primes, S, R, C, out);

    for (int d = 1; d < NN; ++d) {
        int m = NN - d;
        diag_kernel<<<m, 256, 0, stream>>>(R, C, S, d);
    }

    traceback_kernel<<<1, 256, 0, stream>>>(R, C, S, out);
}